// Round 10
// baseline (647.180 us; speedup 1.0000x reference)
//
#include <hip/hip_runtime.h>
#include <stdint.h>
#include <stddef.h>

// ScaledDotProductAttention: B=64, Lq=Lk=2048, D=64, fp32 in/out.
// out tuple = (output [64][2048][64], attn [64][2048][2048]) concat in d_out.
// R10: R9 (all-coalesced global I/O via per-wave LDS redistribution) with
// LDS shrunk 74->45.5KB for 3 WG/CU: single V staging slot + s_red aliased
// into the (Phase-A-only) K region. Goal: 12 waves/CU of TLP on the
// mask-read / attn-write HBM streams.

typedef __attribute__((ext_vector_type(4))) float f32x4;
typedef __fp16 f16x2 __attribute__((ext_vector_type(2)));
typedef __fp16 f16x4 __attribute__((ext_vector_type(4)));
typedef __fp16 f16x8 __attribute__((ext_vector_type(8)));

static constexpr int BATCH = 64;
static constexpr int SEQ   = 2048;
static constexpr int HD    = 64;
static constexpr float NEGH = -60000.0f;  // "-inf" that survives fp16

// per-wave LDS region: 11520 B
//  K slots:  0 + s*2304   (16 rows x 144B, s=0,1)   [Phase A; aliased by s_red at end]
//  VT slot:  4608          (64 d-rows x 40B = 2560)  [Phase B]
//  M/A buf:  7168          (16 q-rows x 272B = 4352) [both phases]

// ---------------- pre-pass: fp32 -> fp16 flat convert ----------------
__global__ void cvt_f16_kernel(const float* __restrict__ in,
                               __fp16* __restrict__ out, int n4) {
  int i = blockIdx.x * blockDim.x + threadIdx.x;
  if (i >= n4) return;
  f32x4 v = *(const f32x4*)(in + (size_t)i * 4);
  f16x4 o;
  o[0] = (__fp16)v[0]; o[1] = (__fp16)v[1];
  o[2] = (__fp16)v[2]; o[3] = (__fp16)v[3];
  *(f16x4*)(out + (size_t)i * 4) = o;
}

// ---------------- main fused attention ----------------
__global__ __launch_bounds__(256, 2) void attn_kernel(
    const __fp16* __restrict__ qh,
    const __fp16* __restrict__ kh,
    const __fp16* __restrict__ vh,
    const float* __restrict__ mask,
    float* __restrict__ out,
    float* __restrict__ attn) {
  __shared__ __align__(16) char pool[4][11520];
  __shared__ float stat_m[4][16];
  __shared__ float stat_l[4][16];

  const int tid  = threadIdx.x;
  const int w    = tid >> 6;
  const int lane = tid & 63;
  const int l15  = lane & 15;
  const int g    = lane >> 4;
  const int g4   = g << 2;
  const int g8   = g << 3;
  const int krow = lane >> 3;        // staging row 0..7
  const int kc16 = (lane & 7) * 16;  // staging byte col

  // XCD remap: XCD x handles batches 8x..8x+7 exclusively (L2 residency)
  const int bid = blockIdx.x;
  const int xcd = bid & 7;
  const int r   = bid >> 3;
  const int b   = xcd * 8 + (r >> 7);
  const int q0  = (r & 127) << 4;
  const int wk0 = w << 9;

  char* wb = pool[w];

  // Q = B operand (col=l15 -> q-row, k'=g*8+j -> head-dim)
  const __fp16* qptr = qh + ((size_t)(b * SEQ + q0 + l15)) * HD;
  const f16x8 qb0 = *(const f16x8*)(qptr + g8);
  const f16x8 qb1 = *(const f16x8*)(qptr + 32 + g8);

  const __fp16* kstrip = kh + ((size_t)(b * SEQ) + wk0) * HD;
  const __fp16* vstrip = vh + ((size_t)(b * SEQ) + wk0) * HD;
  const float*  mbase  = mask + ((size_t)(b * SEQ + q0)) * SEQ + wk0;
  float*        abase  = attn + ((size_t)(b * SEQ + q0)) * SEQ + wk0;

  // 32 named logit fragments
  f16x4 PH0,  PH1,  PH2,  PH3,  PH4,  PH5,  PH6,  PH7;
  f16x4 PH8,  PH9,  PH10, PH11, PH12, PH13, PH14, PH15;
  f16x4 PH16, PH17, PH18, PH19, PH20, PH21, PH22, PH23;
  f16x4 PH24, PH25, PH26, PH27, PH28, PH29, PH30, PH31;

  f16x8 KA0, KB0, KA1, KB1;                  // K staging reg sets
  f32x4 MA0, MA1, MA2, MA3, MB0, MB1, MB2, MB3;  // mask staging sets
  float m = -3.0e38f;

#define ISSUE_K(t, KA, KB)                                                   \
  KA = *(const f16x8*)(kstrip + (size_t)(t) * 1024 + lane * 8);              \
  KB = *(const f16x8*)(kstrip + (size_t)(t) * 1024 + 512 + lane * 8);

#define WRITE_K(s, KA, KB)                                                   \
  *(f16x8*)(wb + (s) * 2304 + krow * 144 + kc16) = KA;                       \
  *(f16x8*)(wb + (s) * 2304 + (8 + krow) * 144 + kc16) = KB;

#define ISSUE_M(c, M0, M1, M2, M3)                                           \
  M0 = *(const f32x4*)(mbase + (size_t)(0 * 4 + g) * SEQ + (c) * 64 + l15 * 4); \
  M1 = *(const f32x4*)(mbase + (size_t)(1 * 4 + g) * SEQ + (c) * 64 + l15 * 4); \
  M2 = *(const f32x4*)(mbase + (size_t)(2 * 4 + g) * SEQ + (c) * 64 + l15 * 4); \
  M3 = *(const f32x4*)(mbase + (size_t)(3 * 4 + g) * SEQ + (c) * 64 + l15 * 4);

#define WRITE_M(M0, M1, M2, M3)                                              \
  *(f32x4*)(wb + 7168 + (0 * 4 + g) * 272 + l15 * 16) = M0;                  \
  *(f32x4*)(wb + 7168 + (1 * 4 + g) * 272 + l15 * 16) = M1;                  \
  *(f32x4*)(wb + 7168 + (2 * 4 + g) * 272 + l15 * 16) = M2;                  \
  *(f32x4*)(wb + 7168 + (3 * 4 + g) * 272 + l15 * 16) = M3;

#define ATILE(t, s, PH)                                                      \
  {                                                                          \
    const f16x8 fa = *(const f16x8*)(wb + (s) * 2304 + l15 * 144 + g * 16);  \
    const f16x8 fb = *(const f16x8*)(wb + (s) * 2304 + l15 * 144 + 64 + g * 16); \
    f32x4 acc = {0.f, 0.f, 0.f, 0.f};                                        \
    acc = __builtin_amdgcn_mfma_f32_16x16x32_f16(fa, qb0, acc, 0, 0, 0);     \
    acc = __builtin_amdgcn_mfma_f32_16x16x32_f16(fb, qb1, acc, 0, 0, 0);     \
    const f32x4 mv = *(const f32x4*)(wb + 7168 + l15 * 272 + ((t) & 3) * 64 + g * 16); \
    float s0 = (mv[0] < 0.f) ? NEGH : fmaf(acc[0], 0.125f, mv[0]);           \
    float s1 = (mv[1] < 0.f) ? NEGH : fmaf(acc[1], 0.125f, mv[1]);           \
    float s2 = (mv[2] < 0.f) ? NEGH : fmaf(acc[2], 0.125f, mv[2]);           \
    float s3 = (mv[3] < 0.f) ? NEGH : fmaf(acc[3], 0.125f, mv[3]);           \
    m = fmaxf(m, fmaxf(fmaxf(s0, s1), fmaxf(s2, s3)));                       \
    f16x2 lo_ = __builtin_amdgcn_cvt_pkrtz(s0, s1);                          \
    f16x2 hi_ = __builtin_amdgcn_cvt_pkrtz(s2, s3);                          \
    PH = (f16x4){lo_[0], lo_[1], hi_[0], hi_[1]};                            \
  }

#define AT0(t, PH)  WRITE_K(0, KA0, KB0) ISSUE_K((t) + 2, KA0, KB0) ATILE(t, 0, PH)
#define AT1(t, PH)  WRITE_K(1, KA1, KB1) ISSUE_K((t) + 2, KA1, KB1) ATILE(t, 1, PH)
#define AT0L(t, PH) WRITE_K(0, KA0, KB0) ATILE(t, 0, PH)
#define AT1L(t, PH) WRITE_K(1, KA1, KB1) ATILE(t, 1, PH)

  // ---- Phase A ----
  ISSUE_K(0, KA0, KB0)
  ISSUE_K(1, KA1, KB1)
  ISSUE_M(0, MA0, MA1, MA2, MA3)

  WRITE_M(MA0, MA1, MA2, MA3) ISSUE_M(1, MB0, MB1, MB2, MB3)
  AT0(0, PH0)  AT1(1, PH1)  AT0(2, PH2)  AT1(3, PH3)
  WRITE_M(MB0, MB1, MB2, MB3) ISSUE_M(2, MA0, MA1, MA2, MA3)
  AT0(4, PH4)  AT1(5, PH5)  AT0(6, PH6)  AT1(7, PH7)
  WRITE_M(MA0, MA1, MA2, MA3) ISSUE_M(3, MB0, MB1, MB2, MB3)
  AT0(8, PH8)  AT1(9, PH9)  AT0(10, PH10) AT1(11, PH11)
  WRITE_M(MB0, MB1, MB2, MB3) ISSUE_M(4, MA0, MA1, MA2, MA3)
  AT0(12, PH12) AT1(13, PH13) AT0(14, PH14) AT1(15, PH15)
  WRITE_M(MA0, MA1, MA2, MA3) ISSUE_M(5, MB0, MB1, MB2, MB3)
  AT0(16, PH16) AT1(17, PH17) AT0(18, PH18) AT1(19, PH19)
  WRITE_M(MB0, MB1, MB2, MB3) ISSUE_M(6, MA0, MA1, MA2, MA3)
  AT0(20, PH20) AT1(21, PH21) AT0(22, PH22) AT1(23, PH23)
  WRITE_M(MA0, MA1, MA2, MA3) ISSUE_M(7, MB0, MB1, MB2, MB3)
  AT0(24, PH24) AT1(25, PH25) AT0(26, PH26) AT1(27, PH27)
  WRITE_M(MB0, MB1, MB2, MB3)
  AT0(28, PH28) AT1(29, PH29) AT0L(30, PH30) AT1L(31, PH31)

#undef AT0
#undef AT1
#undef AT0L
#undef AT1L
#undef ATILE
#undef ISSUE_K
#undef WRITE_K
#undef ISSUE_M
#undef WRITE_M

  // row max across the 4 g-groups holding the same q-row
  m = fmaxf(m, __shfl_xor(m, 16));
  m = fmaxf(m, __shfl_xor(m, 32));

  // ---- Phase A2: e = exp(s - m), sum, repack e over s ----
  float lw = 0.f;
#define A2_STEP(PH)                                                          \
  {                                                                          \
    float e0 = __expf((float)PH[0] - m);                                     \
    float e1 = __expf((float)PH[1] - m);                                     \
    float e2 = __expf((float)PH[2] - m);                                     \
    float e3 = __expf((float)PH[3] - m);                                     \
    lw += (e0 + e1) + (e2 + e3);                                             \
    f16x2 lo_ = __builtin_amdgcn_cvt_pkrtz(e0, e1);                          \
    f16x2 hi_ = __builtin_amdgcn_cvt_pkrtz(e2, e3);                          \
    PH = (f16x4){lo_[0], lo_[1], hi_[0], hi_[1]};                            \
  }
  A2_STEP(PH0)  A2_STEP(PH1)  A2_STEP(PH2)  A2_STEP(PH3)
  A2_STEP(PH4)  A2_STEP(PH5)  A2_STEP(PH6)  A2_STEP(PH7)
  A2_STEP(PH8)  A2_STEP(PH9)  A2_STEP(PH10) A2_STEP(PH11)
  A2_STEP(PH12) A2_STEP(PH13) A2_STEP(PH14) A2_STEP(PH15)
  A2_STEP(PH16) A2_STEP(PH17) A2_STEP(PH18) A2_STEP(PH19)
  A2_STEP(PH20) A2_STEP(PH21) A2_STEP(PH22) A2_STEP(PH23)
  A2_STEP(PH24) A2_STEP(PH25) A2_STEP(PH26) A2_STEP(PH27)
  A2_STEP(PH28) A2_STEP(PH29) A2_STEP(PH30) A2_STEP(PH31)
#undef A2_STEP

  lw += __shfl_xor(lw, 16);
  lw += __shfl_xor(lw, 32);

  if (lane < 16) { stat_m[w][lane] = m; stat_l[w][lane] = lw; }
  __syncthreads();

  float mg = -3.0e38f;
#pragma unroll
  for (int ww = 0; ww < 4; ++ww) mg = fmaxf(mg, stat_m[ww][l15]);
  float lg = 0.f;
#pragma unroll
  for (int ww = 0; ww < 4; ++ww) lg += stat_l[ww][l15] * __expf(stat_m[ww][l15] - mg);
  const float scale = __expf(m - mg) / lg;
  const __fp16 hs = (__fp16)scale;
  const f16x4 sc4 = {hs, hs, hs, hs};

  // ---- Phase B ----
  f32x4 oacc0 = {0.f, 0.f, 0.f, 0.f};
  f32x4 oacc1 = {0.f, 0.f, 0.f, 0.f};
  f32x4 oacc2 = {0.f, 0.f, 0.f, 0.f};
  f32x4 oacc3 = {0.f, 0.f, 0.f, 0.f};

  f16x8 VS0, VS1;  // single V staging reg set

#define ISSUE_V(t)                                                           \
  VS0 = *(const f16x8*)(vstrip + (size_t)(t) * 1024 + lane * 8);             \
  VS1 = *(const f16x8*)(vstrip + (size_t)(t) * 1024 + 512 + lane * 8);

#define WRITE_VT()                                                           \
  {                                                                          \
    char* p_ = wb + 4608 + ((lane & 7) * 8) * 40 + krow * 2;                 \
    *(__fp16*)(p_ + 0 * 40) = VS0[0]; *(__fp16*)(p_ + 1 * 40) = VS0[1];      \
    *(__fp16*)(p_ + 2 * 40) = VS0[2]; *(__fp16*)(p_ + 3 * 40) = VS0[3];      \
    *(__fp16*)(p_ + 4 * 40) = VS0[4]; *(__fp16*)(p_ + 5 * 40) = VS0[5];      \
    *(__fp16*)(p_ + 6 * 40) = VS0[6]; *(__fp16*)(p_ + 7 * 40) = VS0[7];      \
    char* q_ = p_ + 16;                                                      \
    *(__fp16*)(q_ + 0 * 40) = VS1[0]; *(__fp16*)(q_ + 1 * 40) = VS1[1];      \
    *(__fp16*)(q_ + 2 * 40) = VS1[2]; *(__fp16*)(q_ + 3 * 40) = VS1[3];      \
    *(__fp16*)(q_ + 4 * 40) = VS1[4]; *(__fp16*)(q_ + 5 * 40) = VS1[5];      \
    *(__fp16*)(q_ + 6 * 40) = VS1[6]; *(__fp16*)(q_ + 7 * 40) = VS1[7];      \
  }

#define BTILE(t, PH)                                                         \
  {                                                                          \
    const f16x4 pf = PH * sc4;                                               \
    f32x4 st;                                                                \
    st[0] = (float)pf[0]; st[1] = (float)pf[1];                              \
    st[2] = (float)pf[2]; st[3] = (float)pf[3];                              \
    *(f32x4*)(wb + 7168 + l15 * 272 + ((t) & 3) * 64 + g * 16) = st;         \
    const char* vf_ = wb + 4608 + l15 * 40 + g * 8;                          \
    const f16x4 V0_ = *(const f16x4*)(vf_ + 0 * 640);                        \
    const f16x4 V1_ = *(const f16x4*)(vf_ + 1 * 640);                        \
    const f16x4 V2_ = *(const f16x4*)(vf_ + 2 * 640);                        \
    const f16x4 V3_ = *(const f16x4*)(vf_ + 3 * 640);                        \
    oacc0 = __builtin_amdgcn_mfma_f32_16x16x16f16(V0_, pf, oacc0, 0, 0, 0);  \
    oacc1 = __builtin_amdgcn_mfma_f32_16x16x16f16(V1_, pf, oacc1, 0, 0, 0);  \
    oacc2 = __builtin_amdgcn_mfma_f32_16x16x16f16(V2_, pf, oacc2, 0, 0, 0);  \
    oacc3 = __builtin_amdgcn_mfma_f32_16x16x16f16(V3_, pf, oacc3, 0, 0, 0);  \
  }

#define STORE_A(c)                                                           \
  *(f32x4*)(abase + (size_t)(0 * 4 + g) * SEQ + (c) * 64 + l15 * 4) =        \
      *(const f32x4*)(wb + 7168 + (0 * 4 + g) * 272 + l15 * 16);             \
  *(f32x4*)(abase + (size_t)(1 * 4 + g) * SEQ + (c) * 64 + l15 * 4) =        \
      *(const f32x4*)(wb + 7168 + (1 * 4 + g) * 272 + l15 * 16);             \
  *(f32x4*)(abase + (size_t)(2 * 4 + g) * SEQ + (c) * 64 + l15 * 4) =        \
      *(const f32x4*)(wb + 7168 + (2 * 4 + g) * 272 + l15 * 16);             \
  *(f32x4*)(abase + (size_t)(3 * 4 + g) * SEQ + (c) * 64 + l15 * 4) =        \
      *(const f32x4*)(wb + 7168 + (3 * 4 + g) * 272 + l15 * 16);

  // step(t): read slot (t), write slot <- t+1 (already in VS), issue t+2
#define BSTEP(t, PH)                                                         \
  BTILE(t, PH)                                                               \
  WRITE_VT()                                                                 \
  ISSUE_V((t) + 2)
#define BSTEP_T(t, PH)  BTILE(t, PH) WRITE_VT()   /* t = 30 */
#define BSTEP_L(t, PH)  BTILE(t, PH)              /* t = 31 */

  ISSUE_V(0)
  WRITE_VT()
  ISSUE_V(1)

  BSTEP(0, PH0)   BSTEP(1, PH1)   BSTEP(2, PH2)   BSTEP(3, PH3)   STORE_A(0)
  BSTEP(4, PH4)   BSTEP(5, PH5)   BSTEP(6, PH6)   BSTEP(7, PH7)   STORE_A(1)
  BSTEP(8, PH8)   BSTEP(9, PH9)   BSTEP(10, PH10) BSTEP(11, PH11) STORE_A(2)
  BSTEP(12, PH12) BSTEP(13, PH13) BSTEP(14, PH14) BSTEP(15, PH15) STORE_A(3)
  BSTEP(16, PH16) BSTEP(17, PH17) BSTEP(18, PH18) BSTEP(19, PH19) STORE_A(4)
  BSTEP(20, PH20) BSTEP(21, PH21) BSTEP(22, PH22) BSTEP(23, PH23) STORE_A(5)
  BSTEP(24, PH24) BSTEP(25, PH25) BSTEP(26, PH26) BSTEP(27, PH27) STORE_A(6)
  BSTEP(28, PH28) BSTEP(29, PH29) BSTEP_T(30, PH30) BSTEP_L(31, PH31) STORE_A(7)

#undef BSTEP
#undef BSTEP_T
#undef BSTEP_L
#undef BTILE
#undef WRITE_VT
#undef ISSUE_V
#undef STORE_A

  // ---- cross-wave partial-O reduction (s_red aliases per-wave K region) ----
  float* sred_w = (float*)pool[w];
#pragma unroll
  for (int rr = 0; rr < 4; ++rr) {
    sred_w[(0 * 16 + g4 + rr) * 17 + l15] = oacc0[rr];
    sred_w[(1 * 16 + g4 + rr) * 17 + l15] = oacc1[rr];
    sred_w[(2 * 16 + g4 + rr) * 17 + l15] = oacc2[rr];
    sred_w[(3 * 16 + g4 + rr) * 17 + l15] = oacc3[rr];
  }
  __syncthreads();

#pragma unroll
  for (int ii = 0; ii < 4; ++ii) {
    const int i = tid + ii * 256;     // i in [0,1024): q = i>>6, d = i&63
    const int q = i >> 6;
    const int d = i & 63;
    const int o = d * 17 + q;
    float s = ((const float*)pool[0])[o] + ((const float*)pool[1])[o] +
              ((const float*)pool[2])[o] + ((const float*)pool[3])[o];
    out[((size_t)(b * SEQ + q0 + q)) * HD + d] = s;
  }
}

extern "C" void kernel_launch(void* const* d_in, const int* in_sizes, int n_in,
                              void* d_out, int out_size, void* d_ws, size_t ws_size,
                              hipStream_t stream) {
  const float* q    = (const float*)d_in[0];
  const float* k    = (const float*)d_in[1];
  const float* v    = (const float*)d_in[2];
  const float* mask = (const float*)d_in[3];

  float* out  = (float*)d_out;
  float* attn = out + (size_t)BATCH * SEQ * HD;  // tuple: (output, attn)

  const size_t nqk = (size_t)BATCH * SEQ * HD;
  __fp16* qh = (__fp16*)d_ws;
  __fp16* kh = qh + nqk;
  __fp16* vhf = kh + nqk;

  const int n4 = (int)(nqk / 4);
  cvt_f16_kernel<<<dim3((n4 + 255) / 256), dim3(256), 0, stream>>>(q, qh, n4);
  cvt_f16_kernel<<<dim3((n4 + 255) / 256), dim3(256), 0, stream>>>(k, kh, n4);
  cvt_f16_kernel<<<dim3((n4 + 255) / 256), dim3(256), 0, stream>>>(v, vhf, n4);
  attn_kernel<<<dim3(BATCH * (SEQ / 16)), dim3(256), 0, stream>>>(qh, kh, vhf, mask, out, attn);
}

// Round 11
// 585.409 us; speedup vs baseline: 1.1055x; 1.1055x over previous
//
#include <hip/hip_runtime.h>
#include <stdint.h>
#include <stddef.h>

// ScaledDotProductAttention: B=64, Lq=Lk=2048, D=64, fp32 in/out.
// out tuple = (output [64][2048][64], attn [64][2048][2048]) concat in d_out.
// R11: R10 + mask prefetch deepened to 3 groups of lookahead (MA/MB/MC reg
// set rotation, 48 VGPR) so the per-group HBM latency (~900cy) is covered by
// ~3 group periods of issued-ahead loads. Attn stores nontemporal.

typedef __attribute__((ext_vector_type(4))) float f32x4;
typedef __fp16 f16x2 __attribute__((ext_vector_type(2)));
typedef __fp16 f16x4 __attribute__((ext_vector_type(4)));
typedef __fp16 f16x8 __attribute__((ext_vector_type(8)));

static constexpr int BATCH = 64;
static constexpr int SEQ   = 2048;
static constexpr int HD    = 64;
static constexpr float NEGH = -60000.0f;  // "-inf" that survives fp16

// per-wave LDS region: 11520 B
//  K slots:  0 + s*2304   (16 rows x 144B, s=0,1)   [Phase A; aliased by s_red]
//  VT slot:  4608          (64 d-rows x 40B = 2560)  [Phase B]
//  M/A buf:  7168          (16 q-rows x 272B = 4352) [both phases]

// ---------------- pre-pass: fp32 -> fp16 flat convert ----------------
__global__ void cvt_f16_kernel(const float* __restrict__ in,
                               __fp16* __restrict__ out, int n4) {
  int i = blockIdx.x * blockDim.x + threadIdx.x;
  if (i >= n4) return;
  f32x4 v = *(const f32x4*)(in + (size_t)i * 4);
  f16x4 o;
  o[0] = (__fp16)v[0]; o[1] = (__fp16)v[1];
  o[2] = (__fp16)v[2]; o[3] = (__fp16)v[3];
  *(f16x4*)(out + (size_t)i * 4) = o;
}

// ---------------- main fused attention ----------------
__global__ __launch_bounds__(256, 2) void attn_kernel(
    const __fp16* __restrict__ qh,
    const __fp16* __restrict__ kh,
    const __fp16* __restrict__ vh,
    const float* __restrict__ mask,
    float* __restrict__ out,
    float* __restrict__ attn) {
  __shared__ __align__(16) char pool[4][11520];
  __shared__ float stat_m[4][16];
  __shared__ float stat_l[4][16];

  const int tid  = threadIdx.x;
  const int w    = tid >> 6;
  const int lane = tid & 63;
  const int l15  = lane & 15;
  const int g    = lane >> 4;
  const int g4   = g << 2;
  const int g8   = g << 3;
  const int krow = lane >> 3;        // staging row 0..7
  const int kc16 = (lane & 7) * 16;  // staging byte col

  // XCD remap: XCD x handles batches 8x..8x+7 exclusively (L2 residency)
  const int bid = blockIdx.x;
  const int xcd = bid & 7;
  const int r   = bid >> 3;
  const int b   = xcd * 8 + (r >> 7);
  const int q0  = (r & 127) << 4;
  const int wk0 = w << 9;

  char* wb = pool[w];

  // Q = B operand (col=l15 -> q-row, k'=g*8+j -> head-dim)
  const __fp16* qptr = qh + ((size_t)(b * SEQ + q0 + l15)) * HD;
  const f16x8 qb0 = *(const f16x8*)(qptr + g8);
  const f16x8 qb1 = *(const f16x8*)(qptr + 32 + g8);

  const __fp16* kstrip = kh + ((size_t)(b * SEQ) + wk0) * HD;
  const __fp16* vstrip = vh + ((size_t)(b * SEQ) + wk0) * HD;
  const float*  mbase  = mask + ((size_t)(b * SEQ + q0)) * SEQ + wk0;
  float*        abase  = attn + ((size_t)(b * SEQ + q0)) * SEQ + wk0;

  // 32 named logit fragments
  f16x4 PH0,  PH1,  PH2,  PH3,  PH4,  PH5,  PH6,  PH7;
  f16x4 PH8,  PH9,  PH10, PH11, PH12, PH13, PH14, PH15;
  f16x4 PH16, PH17, PH18, PH19, PH20, PH21, PH22, PH23;
  f16x4 PH24, PH25, PH26, PH27, PH28, PH29, PH30, PH31;

  f16x8 KA0, KB0, KA1, KB1;                       // K staging reg sets
  f32x4 MA0, MA1, MA2, MA3;                       // mask set A
  f32x4 MB0, MB1, MB2, MB3;                       // mask set B
  f32x4 MC0, MC1, MC2, MC3;                       // mask set C
  float m = -3.0e38f;

#define ISSUE_K(t, KA, KB)                                                   \
  KA = *(const f16x8*)(kstrip + (size_t)(t) * 1024 + lane * 8);              \
  KB = *(const f16x8*)(kstrip + (size_t)(t) * 1024 + 512 + lane * 8);

#define WRITE_K(s, KA, KB)                                                   \
  *(f16x8*)(wb + (s) * 2304 + krow * 144 + kc16) = KA;                       \
  *(f16x8*)(wb + (s) * 2304 + (8 + krow) * 144 + kc16) = KB;

#define ISSUE_M(c, M0, M1, M2, M3)                                           \
  M0 = __builtin_nontemporal_load((const f32x4*)(mbase + (size_t)(0 * 4 + g) * SEQ + (c) * 64 + l15 * 4)); \
  M1 = __builtin_nontemporal_load((const f32x4*)(mbase + (size_t)(1 * 4 + g) * SEQ + (c) * 64 + l15 * 4)); \
  M2 = __builtin_nontemporal_load((const f32x4*)(mbase + (size_t)(2 * 4 + g) * SEQ + (c) * 64 + l15 * 4)); \
  M3 = __builtin_nontemporal_load((const f32x4*)(mbase + (size_t)(3 * 4 + g) * SEQ + (c) * 64 + l15 * 4));

#define WRITE_M(M0, M1, M2, M3)                                              \
  *(f32x4*)(wb + 7168 + (0 * 4 + g) * 272 + l15 * 16) = M0;                  \
  *(f32x4*)(wb + 7168 + (1 * 4 + g) * 272 + l15 * 16) = M1;                  \
  *(f32x4*)(wb + 7168 + (2 * 4 + g) * 272 + l15 * 16) = M2;                  \
  *(f32x4*)(wb + 7168 + (3 * 4 + g) * 272 + l15 * 16) = M3;

#define ATILE(t, s, PH)                                                      \
  {                                                                          \
    const f16x8 fa = *(const f16x8*)(wb + (s) * 2304 + l15 * 144 + g * 16);  \
    const f16x8 fb = *(const f16x8*)(wb + (s) * 2304 + l15 * 144 + 64 + g * 16); \
    f32x4 acc = {0.f, 0.f, 0.f, 0.f};                                        \
    acc = __builtin_amdgcn_mfma_f32_16x16x32_f16(fa, qb0, acc, 0, 0, 0);     \
    acc = __builtin_amdgcn_mfma_f32_16x16x32_f16(fb, qb1, acc, 0, 0, 0);     \
    const f32x4 mv = *(const f32x4*)(wb + 7168 + l15 * 272 + ((t) & 3) * 64 + g * 16); \
    float s0 = (mv[0] < 0.f) ? NEGH : fmaf(acc[0], 0.125f, mv[0]);           \
    float s1 = (mv[1] < 0.f) ? NEGH : fmaf(acc[1], 0.125f, mv[1]);           \
    float s2 = (mv[2] < 0.f) ? NEGH : fmaf(acc[2], 0.125f, mv[2]);           \
    float s3 = (mv[3] < 0.f) ? NEGH : fmaf(acc[3], 0.125f, mv[3]);           \
    m = fmaxf(m, fmaxf(fmaxf(s0, s1), fmaxf(s2, s3)));                       \
    f16x2 lo_ = __builtin_amdgcn_cvt_pkrtz(s0, s1);                          \
    f16x2 hi_ = __builtin_amdgcn_cvt_pkrtz(s2, s3);                          \
    PH = (f16x4){lo_[0], lo_[1], hi_[0], hi_[1]};                            \
  }

#define AT0(t, PH)  WRITE_K(0, KA0, KB0) ISSUE_K((t) + 2, KA0, KB0) ATILE(t, 0, PH)
#define AT1(t, PH)  WRITE_K(1, KA1, KB1) ISSUE_K((t) + 2, KA1, KB1) ATILE(t, 1, PH)
#define AT0L(t, PH) WRITE_K(0, KA0, KB0) ATILE(t, 0, PH)
#define AT1L(t, PH) WRITE_K(1, KA1, KB1) ATILE(t, 1, PH)

  // ---- Phase A: 3-group mask lookahead (consume c; c+1,c+2 in flight; issue c+3)
  ISSUE_K(0, KA0, KB0)
  ISSUE_K(1, KA1, KB1)
  ISSUE_M(0, MA0, MA1, MA2, MA3)
  ISSUE_M(1, MB0, MB1, MB2, MB3)
  ISSUE_M(2, MC0, MC1, MC2, MC3)

  WRITE_M(MA0, MA1, MA2, MA3) ISSUE_M(3, MA0, MA1, MA2, MA3)
  AT0(0, PH0)  AT1(1, PH1)  AT0(2, PH2)  AT1(3, PH3)
  WRITE_M(MB0, MB1, MB2, MB3) ISSUE_M(4, MB0, MB1, MB2, MB3)
  AT0(4, PH4)  AT1(5, PH5)  AT0(6, PH6)  AT1(7, PH7)
  WRITE_M(MC0, MC1, MC2, MC3) ISSUE_M(5, MC0, MC1, MC2, MC3)
  AT0(8, PH8)  AT1(9, PH9)  AT0(10, PH10) AT1(11, PH11)
  WRITE_M(MA0, MA1, MA2, MA3) ISSUE_M(6, MA0, MA1, MA2, MA3)
  AT0(12, PH12) AT1(13, PH13) AT0(14, PH14) AT1(15, PH15)
  WRITE_M(MB0, MB1, MB2, MB3) ISSUE_M(7, MB0, MB1, MB2, MB3)
  AT0(16, PH16) AT1(17, PH17) AT0(18, PH18) AT1(19, PH19)
  WRITE_M(MC0, MC1, MC2, MC3)
  AT0(20, PH20) AT1(21, PH21) AT0(22, PH22) AT1(23, PH23)
  WRITE_M(MA0, MA1, MA2, MA3)
  AT0(24, PH24) AT1(25, PH25) AT0(26, PH26) AT1(27, PH27)
  WRITE_M(MB0, MB1, MB2, MB3)
  AT0(28, PH28) AT1(29, PH29) AT0L(30, PH30) AT1L(31, PH31)

#undef AT0
#undef AT1
#undef AT0L
#undef AT1L
#undef ATILE
#undef ISSUE_K
#undef WRITE_K
#undef ISSUE_M
#undef WRITE_M

  // row max across the 4 g-groups holding the same q-row
  m = fmaxf(m, __shfl_xor(m, 16));
  m = fmaxf(m, __shfl_xor(m, 32));

  // ---- Phase A2: e = exp(s - m), sum, repack e over s ----
  float lw = 0.f;
#define A2_STEP(PH)                                                          \
  {                                                                          \
    float e0 = __expf((float)PH[0] - m);                                     \
    float e1 = __expf((float)PH[1] - m);                                     \
    float e2 = __expf((float)PH[2] - m);                                     \
    float e3 = __expf((float)PH[3] - m);                                     \
    lw += (e0 + e1) + (e2 + e3);                                             \
    f16x2 lo_ = __builtin_amdgcn_cvt_pkrtz(e0, e1);                          \
    f16x2 hi_ = __builtin_amdgcn_cvt_pkrtz(e2, e3);                          \
    PH = (f16x4){lo_[0], lo_[1], hi_[0], hi_[1]};                            \
  }
  A2_STEP(PH0)  A2_STEP(PH1)  A2_STEP(PH2)  A2_STEP(PH3)
  A2_STEP(PH4)  A2_STEP(PH5)  A2_STEP(PH6)  A2_STEP(PH7)
  A2_STEP(PH8)  A2_STEP(PH9)  A2_STEP(PH10) A2_STEP(PH11)
  A2_STEP(PH12) A2_STEP(PH13) A2_STEP(PH14) A2_STEP(PH15)
  A2_STEP(PH16) A2_STEP(PH17) A2_STEP(PH18) A2_STEP(PH19)
  A2_STEP(PH20) A2_STEP(PH21) A2_STEP(PH22) A2_STEP(PH23)
  A2_STEP(PH24) A2_STEP(PH25) A2_STEP(PH26) A2_STEP(PH27)
  A2_STEP(PH28) A2_STEP(PH29) A2_STEP(PH30) A2_STEP(PH31)
#undef A2_STEP

  lw += __shfl_xor(lw, 16);
  lw += __shfl_xor(lw, 32);

  if (lane < 16) { stat_m[w][lane] = m; stat_l[w][lane] = lw; }
  __syncthreads();

  float mg = -3.0e38f;
#pragma unroll
  for (int ww = 0; ww < 4; ++ww) mg = fmaxf(mg, stat_m[ww][l15]);
  float lg = 0.f;
#pragma unroll
  for (int ww = 0; ww < 4; ++ww) lg += stat_l[ww][l15] * __expf(stat_m[ww][l15] - mg);
  const float scale = __expf(m - mg) / lg;
  const __fp16 hs = (__fp16)scale;
  const f16x4 sc4 = {hs, hs, hs, hs};

  // ---- Phase B ----
  f32x4 oacc0 = {0.f, 0.f, 0.f, 0.f};
  f32x4 oacc1 = {0.f, 0.f, 0.f, 0.f};
  f32x4 oacc2 = {0.f, 0.f, 0.f, 0.f};
  f32x4 oacc3 = {0.f, 0.f, 0.f, 0.f};

  f16x8 VS0, VS1;  // single V staging reg set

#define ISSUE_V(t)                                                           \
  VS0 = *(const f16x8*)(vstrip + (size_t)(t) * 1024 + lane * 8);             \
  VS1 = *(const f16x8*)(vstrip + (size_t)(t) * 1024 + 512 + lane * 8);

#define WRITE_VT()                                                           \
  {                                                                          \
    char* p_ = wb + 4608 + ((lane & 7) * 8) * 40 + krow * 2;                 \
    *(__fp16*)(p_ + 0 * 40) = VS0[0]; *(__fp16*)(p_ + 1 * 40) = VS0[1];      \
    *(__fp16*)(p_ + 2 * 40) = VS0[2]; *(__fp16*)(p_ + 3 * 40) = VS0[3];      \
    *(__fp16*)(p_ + 4 * 40) = VS0[4]; *(__fp16*)(p_ + 5 * 40) = VS0[5];      \
    *(__fp16*)(p_ + 6 * 40) = VS0[6]; *(__fp16*)(p_ + 7 * 40) = VS0[7];      \
    char* q_ = p_ + 16;                                                      \
    *(__fp16*)(q_ + 0 * 40) = VS1[0]; *(__fp16*)(q_ + 1 * 40) = VS1[1];      \
    *(__fp16*)(q_ + 2 * 40) = VS1[2]; *(__fp16*)(q_ + 3 * 40) = VS1[3];      \
    *(__fp16*)(q_ + 4 * 40) = VS1[4]; *(__fp16*)(q_ + 5 * 40) = VS1[5];      \
    *(__fp16*)(q_ + 6 * 40) = VS1[6]; *(__fp16*)(q_ + 7 * 40) = VS1[7];      \
  }

#define BTILE(t, PH)                                                         \
  {                                                                          \
    const f16x4 pf = PH * sc4;                                               \
    f32x4 st;                                                                \
    st[0] = (float)pf[0]; st[1] = (float)pf[1];                              \
    st[2] = (float)pf[2]; st[3] = (float)pf[3];                              \
    *(f32x4*)(wb + 7168 + l15 * 272 + ((t) & 3) * 64 + g * 16) = st;         \
    const char* vf_ = wb + 4608 + l15 * 40 + g * 8;                          \
    const f16x4 V0_ = *(const f16x4*)(vf_ + 0 * 640);                        \
    const f16x4 V1_ = *(const f16x4*)(vf_ + 1 * 640);                        \
    const f16x4 V2_ = *(const f16x4*)(vf_ + 2 * 640);                        \
    const f16x4 V3_ = *(const f16x4*)(vf_ + 3 * 640);                        \
    oacc0 = __builtin_amdgcn_mfma_f32_16x16x16f16(V0_, pf, oacc0, 0, 0, 0);  \
    oacc1 = __builtin_amdgcn_mfma_f32_16x16x16f16(V1_, pf, oacc1, 0, 0, 0);  \
    oacc2 = __builtin_amdgcn_mfma_f32_16x16x16f16(V2_, pf, oacc2, 0, 0, 0);  \
    oacc3 = __builtin_amdgcn_mfma_f32_16x16x16f16(V3_, pf, oacc3, 0, 0, 0);  \
  }

#define STORE_A(c)                                                           \
  __builtin_nontemporal_store(                                               \
      *(const f32x4*)(wb + 7168 + (0 * 4 + g) * 272 + l15 * 16),             \
      (f32x4*)(abase + (size_t)(0 * 4 + g) * SEQ + (c) * 64 + l15 * 4));     \
  __builtin_nontemporal_store(                                               \
      *(const f32x4*)(wb + 7168 + (1 * 4 + g) * 272 + l15 * 16),             \
      (f32x4*)(abase + (size_t)(1 * 4 + g) * SEQ + (c) * 64 + l15 * 4));     \
  __builtin_nontemporal_store(                                               \
      *(const f32x4*)(wb + 7168 + (2 * 4 + g) * 272 + l15 * 16),             \
      (f32x4*)(abase + (size_t)(2 * 4 + g) * SEQ + (c) * 64 + l15 * 4));     \
  __builtin_nontemporal_store(                                               \
      *(const f32x4*)(wb + 7168 + (3 * 4 + g) * 272 + l15 * 16),             \
      (f32x4*)(abase + (size_t)(3 * 4 + g) * SEQ + (c) * 64 + l15 * 4));

  // step(t): read slot (t), write slot <- t+1 (already in VS), issue t+2
#define BSTEP(t, PH)                                                         \
  BTILE(t, PH)                                                               \
  WRITE_VT()                                                                 \
  ISSUE_V((t) + 2)
#define BSTEP_T(t, PH)  BTILE(t, PH) WRITE_VT()   /* t = 30 */
#define BSTEP_L(t, PH)  BTILE(t, PH)              /* t = 31 */

  ISSUE_V(0)
  WRITE_VT()
  ISSUE_V(1)

  BSTEP(0, PH0)   BSTEP(1, PH1)   BSTEP(2, PH2)   BSTEP(3, PH3)   STORE_A(0)
  BSTEP(4, PH4)   BSTEP(5, PH5)   BSTEP(6, PH6)   BSTEP(7, PH7)   STORE_A(1)
  BSTEP(8, PH8)   BSTEP(9, PH9)   BSTEP(10, PH10) BSTEP(11, PH11) STORE_A(2)
  BSTEP(12, PH12) BSTEP(13, PH13) BSTEP(14, PH14) BSTEP(15, PH15) STORE_A(3)
  BSTEP(16, PH16) BSTEP(17, PH17) BSTEP(18, PH18) BSTEP(19, PH19) STORE_A(4)
  BSTEP(20, PH20) BSTEP(21, PH21) BSTEP(22, PH22) BSTEP(23, PH23) STORE_A(5)
  BSTEP(24, PH24) BSTEP(25, PH25) BSTEP(26, PH26) BSTEP(27, PH27) STORE_A(6)
  BSTEP(28, PH28) BSTEP(29, PH29) BSTEP_T(30, PH30) BSTEP_L(31, PH31) STORE_A(7)

#undef BSTEP
#undef BSTEP_T
#undef BSTEP_L
#undef BTILE
#undef WRITE_VT
#undef ISSUE_V
#undef STORE_A

  // ---- cross-wave partial-O reduction (s_red aliases per-wave K region) ----
  float* sred_w = (float*)pool[w];
#pragma unroll
  for (int rr = 0; rr < 4; ++rr) {
    sred_w[(0 * 16 + g4 + rr) * 17 + l15] = oacc0[rr];
    sred_w[(1 * 16 + g4 + rr) * 17 + l15] = oacc1[rr];
    sred_w[(2 * 16 + g4 + rr) * 17 + l15] = oacc2[rr];
    sred_w[(3 * 16 + g4 + rr) * 17 + l15] = oacc3[rr];
  }
  __syncthreads();

#pragma unroll
  for (int ii = 0; ii < 4; ++ii) {
    const int i = tid + ii * 256;     // i in [0,1024): q = i>>6, d = i&63
    const int q = i >> 6;
    const int d = i & 63;
    const int o = d * 17 + q;
    float s = ((const float*)pool[0])[o] + ((const float*)pool[1])[o] +
              ((const float*)pool[2])[o] + ((const float*)pool[3])[o];
    out[((size_t)(b * SEQ + q0 + q)) * HD + d] = s;
  }
}

extern "C" void kernel_launch(void* const* d_in, const int* in_sizes, int n_in,
                              void* d_out, int out_size, void* d_ws, size_t ws_size,
                              hipStream_t stream) {
  const float* q    = (const float*)d_in[0];
  const float* k    = (const float*)d_in[1];
  const float* v    = (const float*)d_in[2];
  const float* mask = (const float*)d_in[3];

  float* out  = (float*)d_out;
  float* attn = out + (size_t)BATCH * SEQ * HD;  // tuple: (output, attn)

  const size_t nqk = (size_t)BATCH * SEQ * HD;
  __fp16* qh = (__fp16*)d_ws;
  __fp16* kh = qh + nqk;
  __fp16* vhf = kh + nqk;

  const int n4 = (int)(nqk / 4);
  cvt_f16_kernel<<<dim3((n4 + 255) / 256), dim3(256), 0, stream>>>(q, qh, n4);
  cvt_f16_kernel<<<dim3((n4 + 255) / 256), dim3(256), 0, stream>>>(k, kh, n4);
  cvt_f16_kernel<<<dim3((n4 + 255) / 256), dim3(256), 0, stream>>>(v, vhf, n4);
  attn_kernel<<<dim3(BATCH * (SEQ / 16)), dim3(256), 0, stream>>>(qh, kh, vhf, mask, out, attn);
}

// Round 12
// 571.431 us; speedup vs baseline: 1.1326x; 1.0245x over previous
//
#include <hip/hip_runtime.h>
#include <stdint.h>
#include <stddef.h>

// ScaledDotProductAttention: B=64, Lq=Lk=2048, D=64, fp32 in/out.
// out tuple = (output [64][2048][64], attn [64][2048][2048]) concat in d_out.
// R12: UNIFORM NEED-ORDER VMEM ISSUE. vmcnt retires in order, so a wait on
// any load drains all older loads; R11's K (2-tile lookahead) issued after
// mask (12-tile) made every K wait eat a fresh mask's HBM latency. Now the
// issue stream mirrors the consume stream with ~8-tile lookahead everywhere:
// K = 8 register sets, mask = 2 group sets interleaved at need position,
// V = 4 sets (Phase B). Everything else identical to R11.

typedef __attribute__((ext_vector_type(4))) float f32x4;
typedef __fp16 f16x2 __attribute__((ext_vector_type(2)));
typedef __fp16 f16x4 __attribute__((ext_vector_type(4)));
typedef __fp16 f16x8 __attribute__((ext_vector_type(8)));

static constexpr int BATCH = 64;
static constexpr int SEQ   = 2048;
static constexpr int HD    = 64;
static constexpr float NEGH = -60000.0f;  // "-inf" that survives fp16

// per-wave LDS region: 11520 B
//  K slots:  0 + s*2304   (16 rows x 144B, s=0,1)   [Phase A; aliased by s_red]
//  VT slot:  4608          (64 d-rows x 40B = 2560)  [Phase B]
//  M/A buf:  7168          (16 q-rows x 272B = 4352) [both phases]

// ---------------- pre-pass: fp32 -> fp16 flat convert ----------------
__global__ void cvt_f16_kernel(const float* __restrict__ in,
                               __fp16* __restrict__ out, int n4) {
  int i = blockIdx.x * blockDim.x + threadIdx.x;
  if (i >= n4) return;
  f32x4 v = *(const f32x4*)(in + (size_t)i * 4);
  f16x4 o;
  o[0] = (__fp16)v[0]; o[1] = (__fp16)v[1];
  o[2] = (__fp16)v[2]; o[3] = (__fp16)v[3];
  *(f16x4*)(out + (size_t)i * 4) = o;
}

// ---------------- main fused attention ----------------
__global__ __launch_bounds__(256, 2) void attn_kernel(
    const __fp16* __restrict__ qh,
    const __fp16* __restrict__ kh,
    const __fp16* __restrict__ vh,
    const float* __restrict__ mask,
    float* __restrict__ out,
    float* __restrict__ attn) {
  __shared__ __align__(16) char pool[4][11520];
  __shared__ float stat_m[4][16];
  __shared__ float stat_l[4][16];

  const int tid  = threadIdx.x;
  const int w    = tid >> 6;
  const int lane = tid & 63;
  const int l15  = lane & 15;
  const int g    = lane >> 4;
  const int g4   = g << 2;
  const int g8   = g << 3;
  const int krow = lane >> 3;        // staging row 0..7
  const int kc16 = (lane & 7) * 16;  // staging byte col

  // XCD remap: XCD x handles batches 8x..8x+7 exclusively (L2 residency)
  const int bid = blockIdx.x;
  const int xcd = bid & 7;
  const int r   = bid >> 3;
  const int b   = xcd * 8 + (r >> 7);
  const int q0  = (r & 127) << 4;
  const int wk0 = w << 9;

  char* wb = pool[w];

  // Q = B operand (col=l15 -> q-row, k'=g*8+j -> head-dim)
  const __fp16* qptr = qh + ((size_t)(b * SEQ + q0 + l15)) * HD;
  const f16x8 qb0 = *(const f16x8*)(qptr + g8);
  const f16x8 qb1 = *(const f16x8*)(qptr + 32 + g8);

  const __fp16* kstrip = kh + ((size_t)(b * SEQ) + wk0) * HD;
  const __fp16* vstrip = vh + ((size_t)(b * SEQ) + wk0) * HD;
  const float*  mbase  = mask + ((size_t)(b * SEQ + q0)) * SEQ + wk0;
  float*        abase  = attn + ((size_t)(b * SEQ + q0)) * SEQ + wk0;

  // 32 named logit fragments
  f16x4 PH0,  PH1,  PH2,  PH3,  PH4,  PH5,  PH6,  PH7;
  f16x4 PH8,  PH9,  PH10, PH11, PH12, PH13, PH14, PH15;
  f16x4 PH16, PH17, PH18, PH19, PH20, PH21, PH22, PH23;
  f16x4 PH24, PH25, PH26, PH27, PH28, PH29, PH30, PH31;

  // K pipeline: 8 named sets (8-tile lookahead)
  f16x8 K0A, K0B, K1A, K1B, K2A, K2B, K3A, K3B;
  f16x8 K4A, K4B, K5A, K5B, K6A, K6B, K7A, K7B;
  // mask pipeline: 2 group sets (2-group = 8-tile lookahead)
  f32x4 MA0, MA1, MA2, MA3;
  f32x4 MB0, MB1, MB2, MB3;
  float m = -3.0e38f;

#define ISSUE_K(t, KA, KB)                                                   \
  KA = *(const f16x8*)(kstrip + (size_t)(t) * 1024 + lane * 8);              \
  KB = *(const f16x8*)(kstrip + (size_t)(t) * 1024 + 512 + lane * 8);

#define WRITE_K(s, KA, KB)                                                   \
  *(f16x8*)(wb + (s) * 2304 + krow * 144 + kc16) = KA;                       \
  *(f16x8*)(wb + (s) * 2304 + (8 + krow) * 144 + kc16) = KB;

#define ISSUE_M(c, M0, M1, M2, M3)                                           \
  M0 = __builtin_nontemporal_load((const f32x4*)(mbase + (size_t)(0 * 4 + g) * SEQ + (c) * 64 + l15 * 4)); \
  M1 = __builtin_nontemporal_load((const f32x4*)(mbase + (size_t)(1 * 4 + g) * SEQ + (c) * 64 + l15 * 4)); \
  M2 = __builtin_nontemporal_load((const f32x4*)(mbase + (size_t)(2 * 4 + g) * SEQ + (c) * 64 + l15 * 4)); \
  M3 = __builtin_nontemporal_load((const f32x4*)(mbase + (size_t)(3 * 4 + g) * SEQ + (c) * 64 + l15 * 4));

#define WRITE_M(M0, M1, M2, M3)                                              \
  *(f32x4*)(wb + 7168 + (0 * 4 + g) * 272 + l15 * 16) = M0;                  \
  *(f32x4*)(wb + 7168 + (1 * 4 + g) * 272 + l15 * 16) = M1;                  \
  *(f32x4*)(wb + 7168 + (2 * 4 + g) * 272 + l15 * 16) = M2;                  \
  *(f32x4*)(wb + 7168 + (3 * 4 + g) * 272 + l15 * 16) = M3;

#define ATILE(t, s, PH)                                                      \
  {                                                                          \
    const f16x8 fa = *(const f16x8*)(wb + (s) * 2304 + l15 * 144 + g * 16);  \
    const f16x8 fb = *(const f16x8*)(wb + (s) * 2304 + l15 * 144 + 64 + g * 16); \
    f32x4 acc = {0.f, 0.f, 0.f, 0.f};                                        \
    acc = __builtin_amdgcn_mfma_f32_16x16x32_f16(fa, qb0, acc, 0, 0, 0);     \
    acc = __builtin_amdgcn_mfma_f32_16x16x32_f16(fb, qb1, acc, 0, 0, 0);     \
    const f32x4 mv = *(const f32x4*)(wb + 7168 + l15 * 272 + ((t) & 3) * 64 + g * 16); \
    float s0 = (mv[0] < 0.f) ? NEGH : fmaf(acc[0], 0.125f, mv[0]);           \
    float s1 = (mv[1] < 0.f) ? NEGH : fmaf(acc[1], 0.125f, mv[1]);           \
    float s2 = (mv[2] < 0.f) ? NEGH : fmaf(acc[2], 0.125f, mv[2]);           \
    float s3 = (mv[3] < 0.f) ? NEGH : fmaf(acc[3], 0.125f, mv[3]);           \
    m = fmaxf(m, fmaxf(fmaxf(s0, s1), fmaxf(s2, s3)));                       \
    f16x2 lo_ = __builtin_amdgcn_cvt_pkrtz(s0, s1);                          \
    f16x2 hi_ = __builtin_amdgcn_cvt_pkrtz(s2, s3);                          \
    PH = (f16x4){lo_[0], lo_[1], hi_[0], hi_[1]};                            \
  }

  // tile step: write K(t) to LDS, re-issue same set for K(t+8), compute
#define AT(t, PH, KA, KB)                                                    \
  WRITE_K((t) & 1, KA, KB) ISSUE_K((t) + 8, KA, KB) ATILE(t, (t) & 1, PH)
#define ATL(t, PH, KA, KB)                                                   \
  WRITE_K((t) & 1, KA, KB) ATILE(t, (t) & 1, PH)

  // ---- Phase A prologue: strict need-order issue ----
  ISSUE_M(0, MA0, MA1, MA2, MA3)
  ISSUE_K(0, K0A, K0B) ISSUE_K(1, K1A, K1B) ISSUE_K(2, K2A, K2B) ISSUE_K(3, K3A, K3B)
  ISSUE_M(1, MB0, MB1, MB2, MB3)
  ISSUE_K(4, K4A, K4B) ISSUE_K(5, K5A, K5B) ISSUE_K(6, K6A, K6B) ISSUE_K(7, K7A, K7B)

  // group 0
  WRITE_M(MA0, MA1, MA2, MA3) ISSUE_M(2, MA0, MA1, MA2, MA3)
  AT(0, PH0, K0A, K0B)  AT(1, PH1, K1A, K1B)  AT(2, PH2, K2A, K2B)  AT(3, PH3, K3A, K3B)
  // group 1
  WRITE_M(MB0, MB1, MB2, MB3) ISSUE_M(3, MB0, MB1, MB2, MB3)
  AT(4, PH4, K4A, K4B)  AT(5, PH5, K5A, K5B)  AT(6, PH6, K6A, K6B)  AT(7, PH7, K7A, K7B)
  // group 2
  WRITE_M(MA0, MA1, MA2, MA3) ISSUE_M(4, MA0, MA1, MA2, MA3)
  AT(8, PH8, K0A, K0B)  AT(9, PH9, K1A, K1B)  AT(10, PH10, K2A, K2B) AT(11, PH11, K3A, K3B)
  // group 3
  WRITE_M(MB0, MB1, MB2, MB3) ISSUE_M(5, MB0, MB1, MB2, MB3)
  AT(12, PH12, K4A, K4B) AT(13, PH13, K5A, K5B) AT(14, PH14, K6A, K6B) AT(15, PH15, K7A, K7B)
  // group 4
  WRITE_M(MA0, MA1, MA2, MA3) ISSUE_M(6, MA0, MA1, MA2, MA3)
  AT(16, PH16, K0A, K0B) AT(17, PH17, K1A, K1B) AT(18, PH18, K2A, K2B) AT(19, PH19, K3A, K3B)
  // group 5
  WRITE_M(MB0, MB1, MB2, MB3) ISSUE_M(7, MB0, MB1, MB2, MB3)
  AT(20, PH20, K4A, K4B) AT(21, PH21, K5A, K5B) AT(22, PH22, K6A, K6B) AT(23, PH23, K7A, K7B)
  // group 6
  WRITE_M(MA0, MA1, MA2, MA3)
  ATL(24, PH24, K0A, K0B) ATL(25, PH25, K1A, K1B) ATL(26, PH26, K2A, K2B) ATL(27, PH27, K3A, K3B)
  // group 7
  WRITE_M(MB0, MB1, MB2, MB3)
  ATL(28, PH28, K4A, K4B) ATL(29, PH29, K5A, K5B) ATL(30, PH30, K6A, K6B) ATL(31, PH31, K7A, K7B)

#undef AT
#undef ATL
#undef ATILE
#undef ISSUE_K
#undef WRITE_K
#undef ISSUE_M
#undef WRITE_M

  // row max across the 4 g-groups holding the same q-row
  m = fmaxf(m, __shfl_xor(m, 16));
  m = fmaxf(m, __shfl_xor(m, 32));

  // ---- Phase A2: e = exp(s - m), sum, repack e over s ----
  float lw = 0.f;
#define A2_STEP(PH)                                                          \
  {                                                                          \
    float e0 = __expf((float)PH[0] - m);                                     \
    float e1 = __expf((float)PH[1] - m);                                     \
    float e2 = __expf((float)PH[2] - m);                                     \
    float e3 = __expf((float)PH[3] - m);                                     \
    lw += (e0 + e1) + (e2 + e3);                                             \
    f16x2 lo_ = __builtin_amdgcn_cvt_pkrtz(e0, e1);                          \
    f16x2 hi_ = __builtin_amdgcn_cvt_pkrtz(e2, e3);                          \
    PH = (f16x4){lo_[0], lo_[1], hi_[0], hi_[1]};                            \
  }
  A2_STEP(PH0)  A2_STEP(PH1)  A2_STEP(PH2)  A2_STEP(PH3)
  A2_STEP(PH4)  A2_STEP(PH5)  A2_STEP(PH6)  A2_STEP(PH7)
  A2_STEP(PH8)  A2_STEP(PH9)  A2_STEP(PH10) A2_STEP(PH11)
  A2_STEP(PH12) A2_STEP(PH13) A2_STEP(PH14) A2_STEP(PH15)
  A2_STEP(PH16) A2_STEP(PH17) A2_STEP(PH18) A2_STEP(PH19)
  A2_STEP(PH20) A2_STEP(PH21) A2_STEP(PH22) A2_STEP(PH23)
  A2_STEP(PH24) A2_STEP(PH25) A2_STEP(PH26) A2_STEP(PH27)
  A2_STEP(PH28) A2_STEP(PH29) A2_STEP(PH30) A2_STEP(PH31)
#undef A2_STEP

  lw += __shfl_xor(lw, 16);
  lw += __shfl_xor(lw, 32);

  if (lane < 16) { stat_m[w][lane] = m; stat_l[w][lane] = lw; }
  __syncthreads();

  float mg = -3.0e38f;
#pragma unroll
  for (int ww = 0; ww < 4; ++ww) mg = fmaxf(mg, stat_m[ww][l15]);
  float lg = 0.f;
#pragma unroll
  for (int ww = 0; ww < 4; ++ww) lg += stat_l[ww][l15] * __expf(stat_m[ww][l15] - mg);
  const float scale = __expf(m - mg) / lg;
  const __fp16 hs = (__fp16)scale;
  const f16x4 sc4 = {hs, hs, hs, hs};

  // ---- Phase B ----
  f32x4 oacc0 = {0.f, 0.f, 0.f, 0.f};
  f32x4 oacc1 = {0.f, 0.f, 0.f, 0.f};
  f32x4 oacc2 = {0.f, 0.f, 0.f, 0.f};
  f32x4 oacc3 = {0.f, 0.f, 0.f, 0.f};

  // V pipeline: 4 named sets (4-tile lookahead)
  f16x8 V0A, V0B, V1A, V1B, V2A, V2B, V3A, V3B;

#define ISSUE_V(t, VA, VB)                                                   \
  VA = *(const f16x8*)(vstrip + (size_t)(t) * 1024 + lane * 8);              \
  VB = *(const f16x8*)(vstrip + (size_t)(t) * 1024 + 512 + lane * 8);

#define WRITE_VT(VA, VB)                                                     \
  {                                                                          \
    char* p_ = wb + 4608 + ((lane & 7) * 8) * 40 + krow * 2;                 \
    *(__fp16*)(p_ + 0 * 40) = VA[0]; *(__fp16*)(p_ + 1 * 40) = VA[1];        \
    *(__fp16*)(p_ + 2 * 40) = VA[2]; *(__fp16*)(p_ + 3 * 40) = VA[3];        \
    *(__fp16*)(p_ + 4 * 40) = VA[4]; *(__fp16*)(p_ + 5 * 40) = VA[5];        \
    *(__fp16*)(p_ + 6 * 40) = VA[6]; *(__fp16*)(p_ + 7 * 40) = VA[7];        \
    char* q_ = p_ + 16;                                                      \
    *(__fp16*)(q_ + 0 * 40) = VB[0]; *(__fp16*)(q_ + 1 * 40) = VB[1];        \
    *(__fp16*)(q_ + 2 * 40) = VB[2]; *(__fp16*)(q_ + 3 * 40) = VB[3];        \
    *(__fp16*)(q_ + 4 * 40) = VB[4]; *(__fp16*)(q_ + 5 * 40) = VB[5];        \
    *(__fp16*)(q_ + 6 * 40) = VB[6]; *(__fp16*)(q_ + 7 * 40) = VB[7];        \
  }

#define BTILE(t, PH)                                                         \
  {                                                                          \
    const f16x4 pf = PH * sc4;                                               \
    f32x4 st;                                                                \
    st[0] = (float)pf[0]; st[1] = (float)pf[1];                              \
    st[2] = (float)pf[2]; st[3] = (float)pf[3];                              \
    *(f32x4*)(wb + 7168 + l15 * 272 + ((t) & 3) * 64 + g * 16) = st;         \
    const char* vf_ = wb + 4608 + l15 * 40 + g * 8;                          \
    const f16x4 Vr0_ = *(const f16x4*)(vf_ + 0 * 640);                       \
    const f16x4 Vr1_ = *(const f16x4*)(vf_ + 1 * 640);                       \
    const f16x4 Vr2_ = *(const f16x4*)(vf_ + 2 * 640);                       \
    const f16x4 Vr3_ = *(const f16x4*)(vf_ + 3 * 640);                       \
    oacc0 = __builtin_amdgcn_mfma_f32_16x16x16f16(Vr0_, pf, oacc0, 0, 0, 0); \
    oacc1 = __builtin_amdgcn_mfma_f32_16x16x16f16(Vr1_, pf, oacc1, 0, 0, 0); \
    oacc2 = __builtin_amdgcn_mfma_f32_16x16x16f16(Vr2_, pf, oacc2, 0, 0, 0); \
    oacc3 = __builtin_amdgcn_mfma_f32_16x16x16f16(Vr3_, pf, oacc3, 0, 0, 0); \
  }

#define STORE_A(c)                                                           \
  __builtin_nontemporal_store(                                               \
      *(const f32x4*)(wb + 7168 + (0 * 4 + g) * 272 + l15 * 16),             \
      (f32x4*)(abase + (size_t)(0 * 4 + g) * SEQ + (c) * 64 + l15 * 4));     \
  __builtin_nontemporal_store(                                               \
      *(const f32x4*)(wb + 7168 + (1 * 4 + g) * 272 + l15 * 16),             \
      (f32x4*)(abase + (size_t)(1 * 4 + g) * SEQ + (c) * 64 + l15 * 4));     \
  __builtin_nontemporal_store(                                               \
      *(const f32x4*)(wb + 7168 + (2 * 4 + g) * 272 + l15 * 16),             \
      (f32x4*)(abase + (size_t)(2 * 4 + g) * SEQ + (c) * 64 + l15 * 4));     \
  __builtin_nontemporal_store(                                               \
      *(const f32x4*)(wb + 7168 + (3 * 4 + g) * 272 + l15 * 16),             \
      (f32x4*)(abase + (size_t)(3 * 4 + g) * SEQ + (c) * 64 + l15 * 4));

  // step t: compute tile t, write tile t+1 to LDS, re-issue set for t+5
#define BSTEP(t, PH, VA, VB)   BTILE(t, PH) WRITE_VT(VA, VB) ISSUE_V((t) + 5, VA, VB)
#define BSTEPN(t, PH, VA, VB)  BTILE(t, PH) WRITE_VT(VA, VB)
#define BSTEPL(t, PH)          BTILE(t, PH)

  // Phase B prologue (need order: V0..V4)
  ISSUE_V(0, V0A, V0B) ISSUE_V(1, V1A, V1B) ISSUE_V(2, V2A, V2B) ISSUE_V(3, V3A, V3B)
  WRITE_VT(V0A, V0B)
  ISSUE_V(4, V0A, V0B)

  BSTEP(0, PH0, V1A, V1B)   BSTEP(1, PH1, V2A, V2B)   BSTEP(2, PH2, V3A, V3B)
  BSTEP(3, PH3, V0A, V0B)   STORE_A(0)
  BSTEP(4, PH4, V1A, V1B)   BSTEP(5, PH5, V2A, V2B)   BSTEP(6, PH6, V3A, V3B)
  BSTEP(7, PH7, V0A, V0B)   STORE_A(1)
  BSTEP(8, PH8, V1A, V1B)   BSTEP(9, PH9, V2A, V2B)   BSTEP(10, PH10, V3A, V3B)
  BSTEP(11, PH11, V0A, V0B) STORE_A(2)
  BSTEP(12, PH12, V1A, V1B) BSTEP(13, PH13, V2A, V2B) BSTEP(14, PH14, V3A, V3B)
  BSTEP(15, PH15, V0A, V0B) STORE_A(3)
  BSTEP(16, PH16, V1A, V1B) BSTEP(17, PH17, V2A, V2B) BSTEP(18, PH18, V3A, V3B)
  BSTEP(19, PH19, V0A, V0B) STORE_A(4)
  BSTEP(20, PH20, V1A, V1B) BSTEP(21, PH21, V2A, V2B) BSTEP(22, PH22, V3A, V3B)
  BSTEP(23, PH23, V0A, V0B) STORE_A(5)
  BSTEP(24, PH24, V1A, V1B) BSTEP(25, PH25, V2A, V2B) BSTEP(26, PH26, V3A, V3B)
  BSTEPN(27, PH27, V0A, V0B) STORE_A(6)
  BSTEPN(28, PH28, V1A, V1B) BSTEPN(29, PH29, V2A, V2B) BSTEPN(30, PH30, V3A, V3B)
  BSTEPL(31, PH31)           STORE_A(7)

#undef BSTEP
#undef BSTEPN
#undef BSTEPL
#undef BTILE
#undef WRITE_VT
#undef ISSUE_V
#undef STORE_A

  // ---- cross-wave partial-O reduction (s_red aliases per-wave K region) ----
  float* sred_w = (float*)pool[w];
#pragma unroll
  for (int rr = 0; rr < 4; ++rr) {
    sred_w[(0 * 16 + g4 + rr) * 17 + l15] = oacc0[rr];
    sred_w[(1 * 16 + g4 + rr) * 17 + l15] = oacc1[rr];
    sred_w[(2 * 16 + g4 + rr) * 17 + l15] = oacc2[rr];
    sred_w[(3 * 16 + g4 + rr) * 17 + l15] = oacc3[rr];
  }
  __syncthreads();

#pragma unroll
  for (int ii = 0; ii < 4; ++ii) {
    const int i = tid + ii * 256;     // i in [0,1024): q = i>>6, d = i&63
    const int q = i >> 6;
    const int d = i & 63;
    const int o = d * 17 + q;
    float s = ((const float*)pool[0])[o] + ((const float*)pool[1])[o] +
              ((const float*)pool[2])[o] + ((const float*)pool[3])[o];
    out[((size_t)(b * SEQ + q0 + q)) * HD + d] = s;
  }
}

extern "C" void kernel_launch(void* const* d_in, const int* in_sizes, int n_in,
                              void* d_out, int out_size, void* d_ws, size_t ws_size,
                              hipStream_t stream) {
  const float* q    = (const float*)d_in[0];
  const float* k    = (const float*)d_in[1];
  const float* v    = (const float*)d_in[2];
  const float* mask = (const float*)d_in[3];

  float* out  = (float*)d_out;
  float* attn = out + (size_t)BATCH * SEQ * HD;  // tuple: (output, attn)

  const size_t nqk = (size_t)BATCH * SEQ * HD;
  __fp16* qh = (__fp16*)d_ws;
  __fp16* kh = qh + nqk;
  __fp16* vhf = kh + nqk;

  const int n4 = (int)(nqk / 4);
  cvt_f16_kernel<<<dim3((n4 + 255) / 256), dim3(256), 0, stream>>>(q, qh, n4);
  cvt_f16_kernel<<<dim3((n4 + 255) / 256), dim3(256), 0, stream>>>(k, kh, n4);
  cvt_f16_kernel<<<dim3((n4 + 255) / 256), dim3(256), 0, stream>>>(v, vhf, n4);
  attn_kernel<<<dim3(BATCH * (SEQ / 16)), dim3(256), 0, stream>>>(qh, kh, vhf, mask, out, attn);
}

// Round 13
// 540.005 us; speedup vs baseline: 1.1985x; 1.0582x over previous
//
#include <hip/hip_runtime.h>
#include <stdint.h>
#include <stddef.h>

// ScaledDotProductAttention: B=64, Lq=Lk=2048, D=64, fp32 in/out.
// out tuple = (output [64][2048][64], attn [64][2048][2048]) concat in d_out.
// R13: fragment-layout pre-passes. Kf/Vf are stored in HBM so that every
// MFMA fragment load in the attn kernel is a contiguous coalesced run
// (K: 2x1KB per tile, V: 4x512B per tile) direct from global (L2-resident).
// Deletes R9-R12's per-wave K staging (128 ds ops) and V byte-transpose
// (512 ds_write_b16 + 128 ds_read). LDS = mask/attn bounce only (17.4KB).
// Need-order VMEM issue (R12) kept: K 8 sets, M 2 group sets, V 4 sets.

typedef __attribute__((ext_vector_type(4))) float f32x4;
typedef __fp16 f16x2 __attribute__((ext_vector_type(2)));
typedef __fp16 f16x4 __attribute__((ext_vector_type(4)));
typedef __fp16 f16x8 __attribute__((ext_vector_type(8)));

static constexpr int BATCH = 64;
static constexpr int SEQ   = 2048;
static constexpr int HD    = 64;
static constexpr float NEGH = -60000.0f;  // "-inf" that survives fp16

// ---------------- pre-pass: K -> fragment layout fp16 ----------------
// Kf[b][kt][half][l15][16B]: lane(g,l15) fragment = 16B at half*1024+l15*64+g*16
// holds K[b][kt*16+l15][half*32 + g*8 .. +7].
__global__ void kfrag_kernel(const float* __restrict__ k, __fp16* __restrict__ kf) {
  const int b    = blockIdx.x >> 5;
  const int ch   = blockIdx.x & 31;
  const int tid  = threadIdx.x;
  const int tl   = tid >> 6;
  const int lane = tid & 63;
  const int l15  = lane & 15;
  const int g    = lane >> 4;
  const int kt   = ch * 4 + tl;
  const float* src = k + ((size_t)(b * SEQ + kt * 16 + l15)) * HD + g * 8;
  char* dst = (char*)kf + ((size_t)(b * 128 + kt)) * 2048 + l15 * 64 + g * 16;
#pragma unroll
  for (int half = 0; half < 2; ++half) {
    f32x4 a = *(const f32x4*)(src + half * 32);
    f32x4 c = *(const f32x4*)(src + half * 32 + 4);
    f16x2 p0 = __builtin_amdgcn_cvt_pkrtz(a[0], a[1]);
    f16x2 p1 = __builtin_amdgcn_cvt_pkrtz(a[2], a[3]);
    f16x2 p2 = __builtin_amdgcn_cvt_pkrtz(c[0], c[1]);
    f16x2 p3 = __builtin_amdgcn_cvt_pkrtz(c[2], c[3]);
    f16x8 o;
    o[0] = p0[0]; o[1] = p0[1]; o[2] = p1[0]; o[3] = p1[1];
    o[4] = p2[0]; o[5] = p2[1]; o[6] = p3[0]; o[7] = p3[1];
    *(f16x8*)(dst + half * 1024) = o;
  }
}

// ---------------- pre-pass: V -> transposed fragment layout fp16 ----------
// Vf[b][kt][db][l15*32 + g*8]: lane(g,l15) 8B = V[b][kt*16+g*4+j][db*16+l15].
__global__ void vfrag_kernel(const float* __restrict__ v, __fp16* __restrict__ vf) {
  __shared__ float tile[64][68];
  const int b   = blockIdx.x >> 5;
  const int ch  = blockIdx.x & 31;
  const int tid = threadIdx.x;
  const int kk  = tid >> 4;
  const int d4  = (tid & 15) << 2;
  const int k0  = ch * 64;
#pragma unroll
  for (int i = 0; i < 4; ++i) {
    f32x4 val = *(const f32x4*)(v + ((size_t)(b * SEQ + k0 + kk + 16 * i)) * HD + d4);
    tile[kk + 16 * i][d4 + 0] = val[0];
    tile[kk + 16 * i][d4 + 1] = val[1];
    tile[kk + 16 * i][d4 + 2] = val[2];
    tile[kk + 16 * i][d4 + 3] = val[3];
  }
  __syncthreads();
  const int tl  = tid >> 6;
  const int db  = (tid >> 4) & 3;
  const int l15 = tid & 15;
  f16x8 o0, o1;
#pragma unroll
  for (int g = 0; g < 2; ++g)
#pragma unroll
    for (int j = 0; j < 4; ++j)
      o0[g * 4 + j] = (__fp16)tile[tl * 16 + g * 4 + j][db * 16 + l15];
#pragma unroll
  for (int g = 0; g < 2; ++g)
#pragma unroll
    for (int j = 0; j < 4; ++j)
      o1[g * 4 + j] = (__fp16)tile[tl * 16 + (g + 2) * 4 + j][db * 16 + l15];
  char* dst = (char*)vf + ((size_t)(b * 128 + ch * 4 + tl)) * 2048 + db * 512 + l15 * 32;
  *(f16x8*)(dst)      = o0;
  *(f16x8*)(dst + 16) = o1;
}

// ---------------- main fused attention ----------------
__global__ __launch_bounds__(256, 2) void attn_kernel(
    const float* __restrict__ q,
    const __fp16* __restrict__ kf,
    const __fp16* __restrict__ vf,
    const float* __restrict__ mask,
    float* __restrict__ out,
    float* __restrict__ attn) {
  __shared__ __align__(16) char pool[4][4352];  // per-wave mask/attn bounce; O-reduce alias
  __shared__ float stat_m[4][16];
  __shared__ float stat_l[4][16];

  const int tid  = threadIdx.x;
  const int w    = tid >> 6;
  const int lane = tid & 63;
  const int l15  = lane & 15;
  const int g    = lane >> 4;
  const int g4   = g << 2;

  // XCD remap: XCD x handles batches 8x..8x+7 exclusively (L2 residency)
  const int bid = blockIdx.x;
  const int xcd = bid & 7;
  const int r   = bid >> 3;
  const int b   = xcd * 8 + (r >> 7);
  const int q0  = (r & 127) << 4;
  const int wk0 = w << 9;

  char* wb = pool[w];
  const int koff = l15 * 64 + g * 16;
  const int voff = l15 * 32 + g * 8;

  const char* kfb = (const char*)kf + ((size_t)(b * 128) + w * 32) * 2048;
  const char* vfb = (const char*)vf + ((size_t)(b * 128) + w * 32) * 2048;
  const float* mbase = mask + ((size_t)(b * SEQ + q0)) * SEQ + wk0;
  float*       abase = attn + ((size_t)(b * SEQ + q0)) * SEQ + wk0;

  // Q fp32 -> fp16 fragments in-kernel (col=l15 -> q-row, k=g*8+j -> d)
  f16x8 qb0, qb1;
  {
    const float* qsrc = q + ((size_t)(b * SEQ + q0 + l15)) * HD + g * 8;
    f32x4 a0 = *(const f32x4*)(qsrc);
    f32x4 a1 = *(const f32x4*)(qsrc + 4);
    f32x4 c0 = *(const f32x4*)(qsrc + 32);
    f32x4 c1 = *(const f32x4*)(qsrc + 36);
    f16x2 p0 = __builtin_amdgcn_cvt_pkrtz(a0[0], a0[1]);
    f16x2 p1 = __builtin_amdgcn_cvt_pkrtz(a0[2], a0[3]);
    f16x2 p2 = __builtin_amdgcn_cvt_pkrtz(a1[0], a1[1]);
    f16x2 p3 = __builtin_amdgcn_cvt_pkrtz(a1[2], a1[3]);
    qb0[0] = p0[0]; qb0[1] = p0[1]; qb0[2] = p1[0]; qb0[3] = p1[1];
    qb0[4] = p2[0]; qb0[5] = p2[1]; qb0[6] = p3[0]; qb0[7] = p3[1];
    p0 = __builtin_amdgcn_cvt_pkrtz(c0[0], c0[1]);
    p1 = __builtin_amdgcn_cvt_pkrtz(c0[2], c0[3]);
    p2 = __builtin_amdgcn_cvt_pkrtz(c1[0], c1[1]);
    p3 = __builtin_amdgcn_cvt_pkrtz(c1[2], c1[3]);
    qb1[0] = p0[0]; qb1[1] = p0[1]; qb1[2] = p1[0]; qb1[3] = p1[1];
    qb1[4] = p2[0]; qb1[5] = p2[1]; qb1[6] = p3[0]; qb1[7] = p3[1];
  }

  // 32 named logit fragments
  f16x4 PH0,  PH1,  PH2,  PH3,  PH4,  PH5,  PH6,  PH7;
  f16x4 PH8,  PH9,  PH10, PH11, PH12, PH13, PH14, PH15;
  f16x4 PH16, PH17, PH18, PH19, PH20, PH21, PH22, PH23;
  f16x4 PH24, PH25, PH26, PH27, PH28, PH29, PH30, PH31;

  // K pipeline: 8 named sets (8-tile lookahead), direct fragment loads
  f16x8 K0A, K0B, K1A, K1B, K2A, K2B, K3A, K3B;
  f16x8 K4A, K4B, K5A, K5B, K6A, K6B, K7A, K7B;
  // mask pipeline: 2 group sets
  f32x4 MA0, MA1, MA2, MA3;
  f32x4 MB0, MB1, MB2, MB3;
  float m = -3.0e38f;

#define ISSUE_K(t, KA, KB)                                                   \
  KA = *(const f16x8*)(kfb + (size_t)(t) * 2048 + koff);                     \
  KB = *(const f16x8*)(kfb + (size_t)(t) * 2048 + 1024 + koff);

#define ISSUE_M(c, M0, M1, M2, M3)                                           \
  M0 = __builtin_nontemporal_load((const f32x4*)(mbase + (size_t)(0 * 4 + g) * SEQ + (c) * 64 + l15 * 4)); \
  M1 = __builtin_nontemporal_load((const f32x4*)(mbase + (size_t)(1 * 4 + g) * SEQ + (c) * 64 + l15 * 4)); \
  M2 = __builtin_nontemporal_load((const f32x4*)(mbase + (size_t)(2 * 4 + g) * SEQ + (c) * 64 + l15 * 4)); \
  M3 = __builtin_nontemporal_load((const f32x4*)(mbase + (size_t)(3 * 4 + g) * SEQ + (c) * 64 + l15 * 4));

#define WRITE_M(M0, M1, M2, M3)                                              \
  *(f32x4*)(wb + (0 * 4 + g) * 272 + l15 * 16) = M0;                         \
  *(f32x4*)(wb + (1 * 4 + g) * 272 + l15 * 16) = M1;                         \
  *(f32x4*)(wb + (2 * 4 + g) * 272 + l15 * 16) = M2;                         \
  *(f32x4*)(wb + (3 * 4 + g) * 272 + l15 * 16) = M3;

#define ATILE(t, PH, KA, KB)                                                 \
  {                                                                          \
    f32x4 acc = {0.f, 0.f, 0.f, 0.f};                                        \
    acc = __builtin_amdgcn_mfma_f32_16x16x32_f16(KA, qb0, acc, 0, 0, 0);     \
    acc = __builtin_amdgcn_mfma_f32_16x16x32_f16(KB, qb1, acc, 0, 0, 0);     \
    const f32x4 mv = *(const f32x4*)(wb + l15 * 272 + ((t) & 3) * 64 + g * 16); \
    float s0 = (mv[0] < 0.f) ? NEGH : fmaf(acc[0], 0.125f, mv[0]);           \
    float s1 = (mv[1] < 0.f) ? NEGH : fmaf(acc[1], 0.125f, mv[1]);           \
    float s2 = (mv[2] < 0.f) ? NEGH : fmaf(acc[2], 0.125f, mv[2]);           \
    float s3 = (mv[3] < 0.f) ? NEGH : fmaf(acc[3], 0.125f, mv[3]);           \
    m = fmaxf(m, fmaxf(fmaxf(s0, s1), fmaxf(s2, s3)));                       \
    f16x2 lo_ = __builtin_amdgcn_cvt_pkrtz(s0, s1);                          \
    f16x2 hi_ = __builtin_amdgcn_cvt_pkrtz(s2, s3);                          \
    PH = (f16x4){lo_[0], lo_[1], hi_[0], hi_[1]};                            \
  }

#define AT(t, PH, KA, KB)  ATILE(t, PH, KA, KB) ISSUE_K((t) + 8, KA, KB)
#define ATL(t, PH, KA, KB) ATILE(t, PH, KA, KB)

  // ---- Phase A prologue: strict need-order issue ----
  ISSUE_M(0, MA0, MA1, MA2, MA3)
  ISSUE_K(0, K0A, K0B) ISSUE_K(1, K1A, K1B) ISSUE_K(2, K2A, K2B) ISSUE_K(3, K3A, K3B)
  ISSUE_M(1, MB0, MB1, MB2, MB3)
  ISSUE_K(4, K4A, K4B) ISSUE_K(5, K5A, K5B) ISSUE_K(6, K6A, K6B) ISSUE_K(7, K7A, K7B)

  WRITE_M(MA0, MA1, MA2, MA3) ISSUE_M(2, MA0, MA1, MA2, MA3)
  AT(0, PH0, K0A, K0B)  AT(1, PH1, K1A, K1B)  AT(2, PH2, K2A, K2B)  AT(3, PH3, K3A, K3B)
  WRITE_M(MB0, MB1, MB2, MB3) ISSUE_M(3, MB0, MB1, MB2, MB3)
  AT(4, PH4, K4A, K4B)  AT(5, PH5, K5A, K5B)  AT(6, PH6, K6A, K6B)  AT(7, PH7, K7A, K7B)
  WRITE_M(MA0, MA1, MA2, MA3) ISSUE_M(4, MA0, MA1, MA2, MA3)
  AT(8, PH8, K0A, K0B)  AT(9, PH9, K1A, K1B)  AT(10, PH10, K2A, K2B) AT(11, PH11, K3A, K3B)
  WRITE_M(MB0, MB1, MB2, MB3) ISSUE_M(5, MB0, MB1, MB2, MB3)
  AT(12, PH12, K4A, K4B) AT(13, PH13, K5A, K5B) AT(14, PH14, K6A, K6B) AT(15, PH15, K7A, K7B)
  WRITE_M(MA0, MA1, MA2, MA3) ISSUE_M(6, MA0, MA1, MA2, MA3)
  AT(16, PH16, K0A, K0B) AT(17, PH17, K1A, K1B) AT(18, PH18, K2A, K2B) AT(19, PH19, K3A, K3B)
  WRITE_M(MB0, MB1, MB2, MB3) ISSUE_M(7, MB0, MB1, MB2, MB3)
  AT(20, PH20, K4A, K4B) AT(21, PH21, K5A, K5B) AT(22, PH22, K6A, K6B) AT(23, PH23, K7A, K7B)
  WRITE_M(MA0, MA1, MA2, MA3)
  ATL(24, PH24, K0A, K0B) ATL(25, PH25, K1A, K1B) ATL(26, PH26, K2A, K2B) ATL(27, PH27, K3A, K3B)
  WRITE_M(MB0, MB1, MB2, MB3)
  ATL(28, PH28, K4A, K4B) ATL(29, PH29, K5A, K5B) ATL(30, PH30, K6A, K6B) ATL(31, PH31, K7A, K7B)

#undef AT
#undef ATL
#undef ATILE
#undef ISSUE_K
#undef ISSUE_M
#undef WRITE_M

  // row max across the 4 g-groups holding the same q-row
  m = fmaxf(m, __shfl_xor(m, 16));
  m = fmaxf(m, __shfl_xor(m, 32));

  // ---- Phase A2: e = exp(s - m), sum, repack e over s ----
  float lw = 0.f;
#define A2_STEP(PH)                                                          \
  {                                                                          \
    float e0 = __expf((float)PH[0] - m);                                     \
    float e1 = __expf((float)PH[1] - m);                                     \
    float e2 = __expf((float)PH[2] - m);                                     \
    float e3 = __expf((float)PH[3] - m);                                     \
    lw += (e0 + e1) + (e2 + e3);                                             \
    f16x2 lo_ = __builtin_amdgcn_cvt_pkrtz(e0, e1);                          \
    f16x2 hi_ = __builtin_amdgcn_cvt_pkrtz(e2, e3);                          \
    PH = (f16x4){lo_[0], lo_[1], hi_[0], hi_[1]};                            \
  }
  A2_STEP(PH0)  A2_STEP(PH1)  A2_STEP(PH2)  A2_STEP(PH3)
  A2_STEP(PH4)  A2_STEP(PH5)  A2_STEP(PH6)  A2_STEP(PH7)
  A2_STEP(PH8)  A2_STEP(PH9)  A2_STEP(PH10) A2_STEP(PH11)
  A2_STEP(PH12) A2_STEP(PH13) A2_STEP(PH14) A2_STEP(PH15)
  A2_STEP(PH16) A2_STEP(PH17) A2_STEP(PH18) A2_STEP(PH19)
  A2_STEP(PH20) A2_STEP(PH21) A2_STEP(PH22) A2_STEP(PH23)
  A2_STEP(PH24) A2_STEP(PH25) A2_STEP(PH26) A2_STEP(PH27)
  A2_STEP(PH28) A2_STEP(PH29) A2_STEP(PH30) A2_STEP(PH31)
#undef A2_STEP

  lw += __shfl_xor(lw, 16);
  lw += __shfl_xor(lw, 32);

  if (lane < 16) { stat_m[w][lane] = m; stat_l[w][lane] = lw; }
  __syncthreads();

  float mg = -3.0e38f;
#pragma unroll
  for (int ww = 0; ww < 4; ++ww) mg = fmaxf(mg, stat_m[ww][l15]);
  float lg = 0.f;
#pragma unroll
  for (int ww = 0; ww < 4; ++ww) lg += stat_l[ww][l15] * __expf(stat_m[ww][l15] - mg);
  const float scale = __expf(m - mg) / lg;
  const __fp16 hs = (__fp16)scale;
  const f16x4 sc4 = {hs, hs, hs, hs};

  // ---- Phase B: direct coalesced V fragment loads + attn via LDS bounce ----
  f32x4 oacc0 = {0.f, 0.f, 0.f, 0.f};
  f32x4 oacc1 = {0.f, 0.f, 0.f, 0.f};
  f32x4 oacc2 = {0.f, 0.f, 0.f, 0.f};
  f32x4 oacc3 = {0.f, 0.f, 0.f, 0.f};

  // V pipeline: 4 named sets x 4 db blocks
  f16x4 V0a, V0b, V0c, V0d, V1a, V1b, V1c, V1d;
  f16x4 V2a, V2b, V2c, V2d, V3a, V3b, V3c, V3d;

#define ISSUE_V(t, Va, Vb, Vc, Vd)                                           \
  Va = *(const f16x4*)(vfb + (size_t)(t) * 2048 + 0 * 512 + voff);           \
  Vb = *(const f16x4*)(vfb + (size_t)(t) * 2048 + 1 * 512 + voff);           \
  Vc = *(const f16x4*)(vfb + (size_t)(t) * 2048 + 2 * 512 + voff);           \
  Vd = *(const f16x4*)(vfb + (size_t)(t) * 2048 + 3 * 512 + voff);

#define BTILE(t, PH, Va, Vb, Vc, Vd)                                         \
  {                                                                          \
    const f16x4 pf = PH * sc4;                                               \
    f32x4 st;                                                                \
    st[0] = (float)pf[0]; st[1] = (float)pf[1];                              \
    st[2] = (float)pf[2]; st[3] = (float)pf[3];                              \
    *(f32x4*)(wb + l15 * 272 + ((t) & 3) * 64 + g * 16) = st;                \
    oacc0 = __builtin_amdgcn_mfma_f32_16x16x16f16(Va, pf, oacc0, 0, 0, 0);   \
    oacc1 = __builtin_amdgcn_mfma_f32_16x16x16f16(Vb, pf, oacc1, 0, 0, 0);   \
    oacc2 = __builtin_amdgcn_mfma_f32_16x16x16f16(Vc, pf, oacc2, 0, 0, 0);   \
    oacc3 = __builtin_amdgcn_mfma_f32_16x16x16f16(Vd, pf, oacc3, 0, 0, 0);   \
  }

#define STORE_A(c)                                                           \
  __builtin_nontemporal_store(                                               \
      *(const f32x4*)(wb + (0 * 4 + g) * 272 + l15 * 16),                    \
      (f32x4*)(abase + (size_t)(0 * 4 + g) * SEQ + (c) * 64 + l15 * 4));     \
  __builtin_nontemporal_store(                                               \
      *(const f32x4*)(wb + (1 * 4 + g) * 272 + l15 * 16),                    \
      (f32x4*)(abase + (size_t)(1 * 4 + g) * SEQ + (c) * 64 + l15 * 4));     \
  __builtin_nontemporal_store(                                               \
      *(const f32x4*)(wb + (2 * 4 + g) * 272 + l15 * 16),                    \
      (f32x4*)(abase + (size_t)(2 * 4 + g) * SEQ + (c) * 64 + l15 * 4));     \
  __builtin_nontemporal_store(                                               \
      *(const f32x4*)(wb + (3 * 4 + g) * 272 + l15 * 16),                    \
      (f32x4*)(abase + (size_t)(3 * 4 + g) * SEQ + (c) * 64 + l15 * 4));

#define BS(t, PH, Va, Vb, Vc, Vd)  BTILE(t, PH, Va, Vb, Vc, Vd) ISSUE_V((t) + 4, Va, Vb, Vc, Vd)
#define BSL(t, PH, Va, Vb, Vc, Vd) BTILE(t, PH, Va, Vb, Vc, Vd)

  ISSUE_V(0, V0a, V0b, V0c, V0d) ISSUE_V(1, V1a, V1b, V1c, V1d)
  ISSUE_V(2, V2a, V2b, V2c, V2d) ISSUE_V(3, V3a, V3b, V3c, V3d)

  BS(0, PH0, V0a, V0b, V0c, V0d)   BS(1, PH1, V1a, V1b, V1c, V1d)
  BS(2, PH2, V2a, V2b, V2c, V2d)   BS(3, PH3, V3a, V3b, V3c, V3d)   STORE_A(0)
  BS(4, PH4, V0a, V0b, V0c, V0d)   BS(5, PH5, V1a, V1b, V1c, V1d)
  BS(6, PH6, V2a, V2b, V2c, V2d)   BS(7, PH7, V3a, V3b, V3c, V3d)   STORE_A(1)
  BS(8, PH8, V0a, V0b, V0c, V0d)   BS(9, PH9, V1a, V1b, V1c, V1d)
  BS(10, PH10, V2a, V2b, V2c, V2d) BS(11, PH11, V3a, V3b, V3c, V3d) STORE_A(2)
  BS(12, PH12, V0a, V0b, V0c, V0d) BS(13, PH13, V1a, V1b, V1c, V1d)
  BS(14, PH14, V2a, V2b, V2c, V2d) BS(15, PH15, V3a, V3b, V3c, V3d) STORE_A(3)
  BS(16, PH16, V0a, V0b, V0c, V0d) BS(17, PH17, V1a, V1b, V1c, V1d)
  BS(18, PH18, V2a, V2b, V2c, V2d) BS(19, PH19, V3a, V3b, V3c, V3d) STORE_A(4)
  BS(20, PH20, V0a, V0b, V0c, V0d) BS(21, PH21, V1a, V1b, V1c, V1d)
  BS(22, PH22, V2a, V2b, V2c, V2d) BS(23, PH23, V3a, V3b, V3c, V3d) STORE_A(5)
  BS(24, PH24, V0a, V0b, V0c, V0d) BS(25, PH25, V1a, V1b, V1c, V1d)
  BS(26, PH26, V2a, V2b, V2c, V2d) BS(27, PH27, V3a, V3b, V3c, V3d) STORE_A(6)
  BSL(28, PH28, V0a, V0b, V0c, V0d) BSL(29, PH29, V1a, V1b, V1c, V1d)
  BSL(30, PH30, V2a, V2b, V2c, V2d) BSL(31, PH31, V3a, V3b, V3c, V3d) STORE_A(7)

#undef BS
#undef BSL
#undef BTILE
#undef ISSUE_V
#undef STORE_A

  // ---- cross-wave partial-O reduction (aliases the per-wave bounce buf) ----
  float* sred_w = (float*)pool[w];   // 1088 floats = 4352 B exactly
#pragma unroll
  for (int rr = 0; rr < 4; ++rr) {
    sred_w[(0 * 16 + g4 + rr) * 17 + l15] = oacc0[rr];
    sred_w[(1 * 16 + g4 + rr) * 17 + l15] = oacc1[rr];
    sred_w[(2 * 16 + g4 + rr) * 17 + l15] = oacc2[rr];
    sred_w[(3 * 16 + g4 + rr) * 17 + l15] = oacc3[rr];
  }
  __syncthreads();

#pragma unroll
  for (int ii = 0; ii < 4; ++ii) {
    const int i = tid + ii * 256;     // i in [0,1024): qq = i>>6, d = i&63
    const int qq = i >> 6;
    const int d = i & 63;
    const int o = d * 17 + qq;
    float s = ((const float*)pool[0])[o] + ((const float*)pool[1])[o] +
              ((const float*)pool[2])[o] + ((const float*)pool[3])[o];
    out[((size_t)(b * SEQ + q0 + qq)) * HD + d] = s;
  }
}

extern "C" void kernel_launch(void* const* d_in, const int* in_sizes, int n_in,
                              void* d_out, int out_size, void* d_ws, size_t ws_size,
                              hipStream_t stream) {
  const float* q    = (const float*)d_in[0];
  const float* k    = (const float*)d_in[1];
  const float* v    = (const float*)d_in[2];
  const float* mask = (const float*)d_in[3];

  float* out  = (float*)d_out;
  float* attn = out + (size_t)BATCH * SEQ * HD;  // tuple: (output, attn)

  const size_t nqk = (size_t)BATCH * SEQ * HD;
  __fp16* kfrag = (__fp16*)d_ws;
  __fp16* vfrag = kfrag + nqk;

  kfrag_kernel<<<dim3(BATCH * 32), dim3(256), 0, stream>>>(k, kfrag);
  vfrag_kernel<<<dim3(BATCH * 32), dim3(256), 0, stream>>>(v, vfrag);
  attn_kernel<<<dim3(BATCH * (SEQ / 16)), dim3(256), 0, stream>>>(q, kfrag, vfrag, mask, out, attn);
}